// Round 8
// baseline (717.612 us; speedup 1.0000x reference)
//
#include <hip/hip_runtime.h>
#include <hip/hip_bf16.h>

#define BATCH 8
#define HDIM 64
#define WDIM 64
#define CC 384
#define NHE 12
#define HD 32
#define NTOK 32768  // BATCH*HDIM*WDIM
#define NBLK 2

typedef short short8 __attribute__((ext_vector_type(8)));
typedef float f32x4 __attribute__((ext_vector_type(4)));

__device__ __forceinline__ float bf2f(unsigned short u) {
  return __uint_as_float(((unsigned int)u) << 16);
}
__device__ __forceinline__ unsigned short f2bf(float f) {
  __hip_bfloat16 h = __float2bfloat16(f);
  return *reinterpret_cast<unsigned short*>(&h);
}
__device__ __forceinline__ float wave_sum(float s) {
#pragma unroll
  for (int o = 32; o; o >>= 1) s += __shfl_xor(s, o, 64);
  return s;
}
__device__ __forceinline__ float gelu_f(float x) {
  float y = 0.7978845608028654f * (x + 0.044715f * x * x * x);
  float t = 1.0f - 2.0f / (__expf(2.0f * y) + 1.0f);
  return 0.5f * x * (1.0f + t);
}
__device__ __forceinline__ int regid(int x) {
  return x < 56 ? 0 : (x < 60 ? 1 : 2);
}
// async global->LDS, 16B per lane; lds dest = wave-uniform base + lane*16
__device__ __forceinline__ void gload16(const void* g, void* l) {
  __builtin_amdgcn_global_load_lds(
      (const __attribute__((address_space(1))) unsigned int*)g,
      (__attribute__((address_space(3))) unsigned int*)l, 16, 0, 0);
}

// ---- weight transpose + bf16 cast: src (K,N) f32 -> dst (N,K) bf16 ----
__global__ __launch_bounds__(256) void wconv_kernel(
    const float* __restrict__ src, unsigned short* __restrict__ dst, int K, int N) {
  __shared__ float tile[64 * 65];
  const int bn = blockIdx.x * 64, bk = blockIdx.y * 64;
  const int t = threadIdx.x;
  const int lk = t >> 2, ln = (t & 3) * 16;
  const float* ps = src + (size_t)(bk + lk) * N + bn + ln;
#pragma unroll
  for (int j = 0; j < 4; ++j)
    *(float4*)&tile[lk * 65 + ln + 4 * j] = *(const float4*)(ps + 4 * j);
  __syncthreads();
  const int on = t >> 2, ok = (t & 3) * 16;
  unsigned short ob[16];
#pragma unroll
  for (int j = 0; j < 16; ++j) ob[j] = f2bf(tile[(ok + j) * 65 + on]);
  uint4* pd = (uint4*)(dst + (size_t)(bn + on) * K + bk + ok);
  pd[0] = ((const uint4*)ob)[0];
  pd[1] = ((const uint4*)ob)[1];
}

// ---- bias table prep: biasT[h][n][m] = rpb[relidx(n,m)*12 + h] ----
__global__ __launch_bounds__(256) void bias_prep_kernel(
    const float* __restrict__ rpb, float* __restrict__ biasT) {
  int idx = blockIdx.x * 256 + threadIdx.x;  // 12*64*64 = 49152
  int m = idx & 63;
  int n = (idx >> 6) & 63;
  int h = idx >> 12;
  int dr = (n >> 3) - (m >> 3) + 7;
  int dc = (n & 7) - (m & 7) + 7;
  biasT[idx] = rpb[(dr * 15 + dc) * NHE + h];
}

// ---- fused outer-LN + LN1 + shift + window partition ----
// y0h (bf16 token-major) = LN(xin)*og+ob ; abuf (bf16 window-major) = LN1 result
__global__ __launch_bounds__(256) void ln_fused_kernel(
    const float* __restrict__ xin, const float* __restrict__ og,
    const float* __restrict__ ob, const float* __restrict__ n1g,
    const float* __restrict__ n1b, unsigned short* __restrict__ y0h,
    unsigned short* __restrict__ abuf, int shift) {
  const int lane = threadIdx.x & 63;
  const int token = blockIdx.x * 4 + (threadIdx.x >> 6);
  const float* px = xin + (size_t)token * CC;
  float v[6];
#pragma unroll
  for (int j = 0; j < 6; ++j) v[j] = px[j * 64 + lane];
  float s = 0.f;
#pragma unroll
  for (int j = 0; j < 6; ++j) s += v[j];
  s = wave_sum(s);
  float mean = s * (1.0f / CC);
  float q = 0.f;
#pragma unroll
  for (int j = 0; j < 6; ++j) { float d = v[j] - mean; q += d * d; }
  q = wave_sum(q);
  float rstd = rsqrtf(q * (1.0f / CC) + 1e-5f);
  unsigned short* py = y0h + (size_t)token * CC;
#pragma unroll
  for (int j = 0; j < 6; ++j) {
    int d = j * 64 + lane;
    float y = (v[j] - mean) * rstd * og[d] + ob[d];
    py[d] = f2bf(y);
    v[j] = y;
  }
  s = 0.f;
#pragma unroll
  for (int j = 0; j < 6; ++j) s += v[j];
  s = wave_sum(s);
  float mean2 = s * (1.0f / CC);
  q = 0.f;
#pragma unroll
  for (int j = 0; j < 6; ++j) { float d = v[j] - mean2; q += d * d; }
  q = wave_sum(q);
  float rstd2 = rsqrtf(q * (1.0f / CC) + 1e-5f);
  int b = token >> 12;
  int hh = (token >> 6) & 63;
  int ww = token & 63;
  int r = (hh - shift) & 63;
  int c = (ww - shift) & 63;
  int wrow = (((b << 6) + ((r >> 3) << 3) + (c >> 3)) << 6) + ((r & 7) << 3) + (c & 7);
  unsigned short* pa = abuf + (size_t)wrow * CC;
#pragma unroll
  for (int j = 0; j < 6; ++j) {
    int d = j * 64 + lane;
    pa[d] = f2bf((v[j] - mean2) * rstd2 * n1g[d] + n1b[d]);
  }
}

// ---- LN2: x1 (bf16 token-major) -> abuf (bf16 token-major) ----
__global__ __launch_bounds__(256) void ln2_kernel(
    const unsigned short* __restrict__ x1h, const float* __restrict__ g2,
    const float* __restrict__ b2, unsigned short* __restrict__ abuf) {
  const int lane = threadIdx.x & 63;
  const int token = blockIdx.x * 4 + (threadIdx.x >> 6);
  const unsigned short* px = x1h + (size_t)token * CC;
  float v[6];
#pragma unroll
  for (int j = 0; j < 6; ++j) v[j] = bf2f(px[j * 64 + lane]);
  float s = 0.f;
#pragma unroll
  for (int j = 0; j < 6; ++j) s += v[j];
  s = wave_sum(s);
  float mean = s * (1.0f / CC);
  float q = 0.f;
#pragma unroll
  for (int j = 0; j < 6; ++j) { float d = v[j] - mean; q += d * d; }
  q = wave_sum(q);
  float rstd = rsqrtf(q * (1.0f / CC) + 1e-5f);
  unsigned short* pa = abuf + (size_t)token * CC;
#pragma unroll
  for (int j = 0; j < 6; ++j) {
    int d = j * 64 + lane;
    pa[d] = f2bf((v[j] - mean) * rstd * g2[d] + b2[d]);
  }
}

// ---- MFMA windowed attention ----
__global__ __launch_bounds__(256, 2) void attn_mfma_kernel(
    const unsigned short* __restrict__ qkv, const float* __restrict__ biasT,
    unsigned short* __restrict__ aout, int use_mask) {
  __shared__ char smem[55296];
  const int tid = threadIdx.x;
  const int wv = tid >> 6;
  const int lane = tid & 63;
  const int l0 = lane & 15;
  const int q = lane >> 4;
  const int wi = blockIdx.x / 3;
  const int hg = blockIdx.x - wi * 3;
  const int h = hg * 4 + wv;

  unsigned short* Pl = (unsigned short*)(smem + wv * 13824);
  unsigned short* Vt = (unsigned short*)(smem + wv * 13824 + 9216);

  const unsigned short* qbase = qkv + (size_t)(wi * 64) * 1152 + h * HD;

  short8 kf[4], qf[4];
#pragma unroll
  for (int mt = 0; mt < 4; ++mt)
    kf[mt] = *(const short8*)(qbase + (size_t)(16 * mt + l0) * 1152 + CC + 8 * q);
#pragma unroll
  for (int nt = 0; nt < 4; ++nt)
    qf[nt] = *(const short8*)(qbase + (size_t)(16 * nt + l0) * 1152 + 8 * q);

  f32x4 acc[4][4];
  const float* bh = biasT + h * 4096;
#pragma unroll
  for (int mt = 0; mt < 4; ++mt)
#pragma unroll
    for (int nt = 0; nt < 4; ++nt)
      acc[mt][nt] = *(const f32x4*)(bh + (l0 + 16 * nt) * 64 + 16 * mt + 4 * q);

  unsigned short varr[32];
  {
    const uint4* pv = (const uint4*)(qbase + (size_t)lane * 1152 + 2 * CC);
    uint4* t4 = (uint4*)varr;
    t4[0] = pv[0]; t4[1] = pv[1]; t4[2] = pv[2]; t4[3] = pv[3];
#pragma unroll
    for (int d = 0; d < 32; ++d) Vt[d * 72 + lane] = varr[d];
  }

#pragma unroll
  for (int mt = 0; mt < 4; ++mt)
#pragma unroll
    for (int nt = 0; nt < 4; ++nt)
      acc[mt][nt] = __builtin_amdgcn_mfma_f32_16x16x32_bf16(kf[mt], qf[nt], acc[mt][nt], 0, 0, 0);

  if (use_mask) {
    int wloc = wi & 63;
    int wy = (wloc >> 3) * 8, wx = (wloc & 7) * 8;
    int idn[4], idm[16];
#pragma unroll
    for (int nt = 0; nt < 4; ++nt) {
      int n = l0 + 16 * nt;
      idn[nt] = regid(wy + (n >> 3)) * 3 + regid(wx + (n & 7));
    }
#pragma unroll
    for (int mt = 0; mt < 4; ++mt)
#pragma unroll
      for (int r = 0; r < 4; ++r) {
        int m = 16 * mt + 4 * q + r;
        idm[mt * 4 + r] = regid(wy + (m >> 3)) * 3 + regid(wx + (m & 7));
      }
#pragma unroll
    for (int mt = 0; mt < 4; ++mt)
#pragma unroll
      for (int nt = 0; nt < 4; ++nt)
#pragma unroll
        for (int r = 0; r < 4; ++r)
          acc[mt][nt][r] += (idm[mt * 4 + r] == idn[nt]) ? 0.0f : -100.0f;
  }

  float mx[4], inv[4];
#pragma unroll
  for (int nt = 0; nt < 4; ++nt) {
    float m0 = -1e30f;
#pragma unroll
    for (int mt = 0; mt < 4; ++mt)
#pragma unroll
      for (int r = 0; r < 4; ++r) m0 = fmaxf(m0, acc[mt][nt][r]);
    m0 = fmaxf(m0, __shfl_xor(m0, 16, 64));
    m0 = fmaxf(m0, __shfl_xor(m0, 32, 64));
    mx[nt] = m0;
  }
#pragma unroll
  for (int nt = 0; nt < 4; ++nt) {
    float s0 = 0.f;
#pragma unroll
    for (int mt = 0; mt < 4; ++mt)
#pragma unroll
      for (int r = 0; r < 4; ++r) {
        float e = __expf(acc[mt][nt][r] - mx[nt]);
        acc[mt][nt][r] = e;
        s0 += e;
      }
    s0 += __shfl_xor(s0, 16, 64);
    s0 += __shfl_xor(s0, 32, 64);
    inv[nt] = 1.0f / s0;
  }

#pragma unroll
  for (int mt = 0; mt < 4; ++mt)
#pragma unroll
    for (int nt = 0; nt < 4; ++nt) {
      unsigned int lo = (unsigned int)f2bf(acc[mt][nt][0] * inv[nt]) |
                        ((unsigned int)f2bf(acc[mt][nt][1] * inv[nt]) << 16);
      unsigned int hi = (unsigned int)f2bf(acc[mt][nt][2] * inv[nt]) |
                        ((unsigned int)f2bf(acc[mt][nt][3] * inv[nt]) << 16);
      unsigned int* dst = (unsigned int*)(Pl + (l0 + 16 * nt) * 72 + 16 * mt + 4 * q);
      dst[0] = lo;
      dst[1] = hi;
    }
  __syncthreads();

  f32x4 oacc[4][2] = {};
#pragma unroll
  for (int kt = 0; kt < 2; ++kt) {
    short8 pa[4], vb[2];
#pragma unroll
    for (int nt = 0; nt < 4; ++nt)
      pa[nt] = *(const short8*)(Pl + (l0 + 16 * nt) * 72 + 8 * q + 32 * kt);
#pragma unroll
    for (int dt = 0; dt < 2; ++dt)
      vb[dt] = *(const short8*)(Vt + (l0 + 16 * dt) * 72 + 8 * q + 32 * kt);
#pragma unroll
    for (int nt = 0; nt < 4; ++nt)
#pragma unroll
      for (int dt = 0; dt < 2; ++dt)
        oacc[nt][dt] = __builtin_amdgcn_mfma_f32_16x16x32_bf16(pa[nt], vb[dt], oacc[nt][dt], 0, 0, 0);
  }
  __syncthreads();

  float* Ol = (float*)Pl;
#pragma unroll
  for (int nt = 0; nt < 4; ++nt)
#pragma unroll
    for (int dt = 0; dt < 2; ++dt)
#pragma unroll
      for (int r = 0; r < 4; ++r)
        Ol[(16 * nt + 4 * q + r) * 36 + l0 + 16 * dt] = oacc[nt][dt][r];
  __syncthreads();
  unsigned short ob[32];
#pragma unroll
  for (int j = 0; j < 32; ++j) ob[j] = f2bf(Ol[lane * 36 + j]);
  uint4* po = (uint4*)(aout + ((size_t)wi * 64 + lane) * CC + h * HD);
  const uint4* so = (const uint4*)ob;
  po[0] = so[0]; po[1] = so[1]; po[2] = so[2]; po[3] = so[3];
}

// ---- GEMM v8: 3-slot DMA ring, BK=32, raw s_barrier + manual vmcnt.
// Steady state: waitcnt vmcnt(4) lands iter i while iter i+1's 4 loads stay
// in flight across the barrier (never drain to 0 mid-loop); issue iter i+2;
// compute iter i. 48 KB LDS -> 2-3 blocks/CU; sustained outstanding ~32 KB
// per block. No register VMEM in the K-loop (vmcnt purity). XOR-swizzled
// unpadded LDS (dense collective reads, 0 conflicts). Grid x=colTiles.
// C[M, NN] = A[M,KK](bf16) @ Bt[NN,KK]^T(bf16) + bias, fused epilogues:
// EPI 0: +bias, scale q-cols -> bf16 (QKV)
// EPI 1: +bias, gelu -> bf16 (MLP1)
// EPI 2: +bias, un-window/un-shift scatter, + add0h(y0 bf16) -> bf16 (PROJ -> x1)
// EPI 3: +bias, + add0h(x1 bf16) + add1f(xv fp32) -> fp32 (MLP2 -> out)
template <int EPI, int NN, int KK>
__global__ __launch_bounds__(256, 2) void gemm_kernel(
    const unsigned short* __restrict__ A, const unsigned short* __restrict__ Bt,
    const float* __restrict__ bias, float* __restrict__ outf,
    unsigned short* __restrict__ outb, const unsigned short* __restrict__ add0h,
    const float* __restrict__ add1f, int shift) {
  constexpr int ITERS = KK / 32;
  __shared__ __align__(1024) char smem[49152];  // 3 slots x (A 8K | B 8K)
  const int tid = threadIdx.x;
  const int lane = tid & 63;
  const int wv = tid >> 6;
  const int wm = wv & 1, wn = wv >> 1;
  const int rowBase = blockIdx.y * 128;
  const int colBase = blockIdx.x * 128;
  // staging: each gload16 covers one 16-row group; lane -> row lane>>2,
  // dest chunk lane&3, source chunk xor-swizzled (row length = 4x16B chunks)
  const int rloc = lane >> 2;
  const int cpos = lane & 3;
  const int schunk = cpos ^ (rloc & 3);
  const unsigned short* pAl = A + (size_t)(rowBase + rloc) * KK + 8 * schunk;
  const unsigned short* pBl = Bt + (size_t)(colBase + rloc) * KK + 8 * schunk;
  const int l0 = lane & 15;
  const int q = lane >> 4;
  f32x4 acc[4][4] = {};
  const int g0 = wv, g1 = wv + 4;  // this wave's two 16-row groups

  auto issue = [&](int it, int slot) {
    char* sp = smem + slot * 16384;
    const size_t k0 = (size_t)it * 32;
    gload16(pAl + (size_t)(16 * g0) * KK + k0, sp + g0 * 1024);
    gload16(pAl + (size_t)(16 * g1) * KK + k0, sp + g1 * 1024);
    gload16(pBl + (size_t)(16 * g0) * KK + k0, sp + 8192 + g0 * 1024);
    gload16(pBl + (size_t)(16 * g1) * KK + k0, sp + 8192 + g1 * 1024);
  };
  auto compute = [&](int slot) {
    const unsigned short* As = (const unsigned short*)(smem + slot * 16384);
    const unsigned short* Bs = As + 4096;
    short8 af[4], bfr[4];
#pragma unroll
    for (int im = 0; im < 4; ++im) {
      int r = wm * 64 + im * 16 + l0;
      af[im] = *(const short8*)&As[r * 32 + 8 * (q ^ (r & 3))];
    }
#pragma unroll
    for (int in_ = 0; in_ < 4; ++in_) {
      int r = wn * 64 + in_ * 16 + l0;
      bfr[in_] = *(const short8*)&Bs[r * 32 + 8 * (q ^ (r & 3))];
    }
#pragma unroll
    for (int im = 0; im < 4; ++im)
#pragma unroll
      for (int in_ = 0; in_ < 4; ++in_)
        acc[im][in_] = __builtin_amdgcn_mfma_f32_16x16x32_bf16(
            af[im], bfr[in_], acc[im][in_], 0, 0, 0);
  };

  issue(0, 0);
  issue(1, 1);
  int sc_cur = 0;   // slot of iter i
  int sc_nxt = 2;   // slot for iter i+2
  for (int i = 0; i < ITERS - 1; ++i) {
    __builtin_amdgcn_s_waitcnt(0x0F74);  // vmcnt(4): iter i landed, i+1 in flight
    __builtin_amdgcn_s_barrier();
    if (i + 2 < ITERS) issue(i + 2, sc_nxt);
    compute(sc_cur);
    sc_cur = (sc_cur == 2) ? 0 : sc_cur + 1;
    sc_nxt = (sc_nxt == 2) ? 0 : sc_nxt + 1;
  }
  __builtin_amdgcn_s_waitcnt(0x0F70);    // vmcnt(0): last iter landed
  __builtin_amdgcn_s_barrier();
  compute(sc_cur);

  const int quad = lane >> 4;
  const int lc = lane & 15;
#pragma unroll
  for (int im = 0; im < 4; ++im) {
    int rb = rowBase + wm * 64 + im * 16 + quad * 4;
#pragma unroll
    for (int in_ = 0; in_ < 4; ++in_) {
      int gcol = colBase + wn * 64 + in_ * 16 + lc;
      float bv = bias[gcol];
#pragma unroll
      for (int r = 0; r < 4; ++r) {
        int grow = rb + r;
        float v = acc[im][in_][r] + bv;
        if (EPI == 0) {
          if (gcol < CC) v *= 0.17677669529663687f;  // fold q-scale into QKV
          outb[(size_t)grow * NN + gcol] = f2bf(v);
        } else if (EPI == 1) {
          outb[(size_t)grow * NN + gcol] = f2bf(gelu_f(v));
        } else if (EPI == 2) {
          int b = grow >> 12;
          int wl = (grow >> 6) & 63;
          int t = grow & 63;
          int rr = ((wl >> 3) << 3) + (t >> 3);
          int cc = ((wl & 7) << 3) + (t & 7);
          int hh2 = (rr + shift) & 63;
          int ww2 = (cc + shift) & 63;
          size_t dst = ((size_t)((b << 6) + hh2) * 64 + ww2) * CC + gcol;
          outb[dst] = f2bf(bf2f(add0h[dst]) + v);
        } else {
          size_t dst = (size_t)grow * CC + gcol;
          outf[dst] = bf2f(add0h[dst]) + add1f[dst] + v;
        }
      }
    }
  }
}

extern "C" void kernel_launch(void* const* d_in, const int* in_sizes, int n_in,
                              void* d_out, int out_size, void* d_ws, size_t ws_size,
                              hipStream_t stream) {
  const float* x    = (const float*)d_in[0];
  const float* og   = (const float*)d_in[1];
  const float* ob   = (const float*)d_in[2];
  const float* n1g  = (const float*)d_in[3];
  const float* n1b  = (const float*)d_in[4];
  const float* n2g  = (const float*)d_in[5];
  const float* n2b  = (const float*)d_in[6];
  const float* qkvw = (const float*)d_in[7];
  const float* qkvb = (const float*)d_in[8];
  const float* pw   = (const float*)d_in[9];
  const float* pb   = (const float*)d_in[10];
  const float* w1   = (const float*)d_in[11];
  const float* b1   = (const float*)d_in[12];
  const float* w2   = (const float*)d_in[13];
  const float* b2   = (const float*)d_in[14];
  const float* rpb  = (const float*)d_in[15];
  float* out = (float*)d_out;

  char* ws = (char*)d_ws;
  unsigned short* y0h   = (unsigned short*)(ws);              // 25165824 B
  unsigned short* x1h   = (unsigned short*)(ws + 25165824);   // 25165824 B
  unsigned short* a_bf  = (unsigned short*)(ws + 50331648);   // 25165824 B
  unsigned short* at_bf = (unsigned short*)(ws + 75497472);   // 25165824 B
  unsigned short* big_bf= (unsigned short*)(ws + 100663296);  // 100663296 B (qkv/mlp1 union)
  unsigned short* wt    = (unsigned short*)(ws + 201326592);  // 7077888 B
  float* biasT          = (float*)(ws + 100663296 + 75497472);  // 196608 B (tail of big_bf)

  for (int i = 0; i < NBLK; ++i) {
    unsigned short* wq = wt + (size_t)i * 1769472;
    wconv_kernel<<<dim3(18, 6), 256, 0, stream>>>(qkvw + (size_t)i * 442368, wq, 384, 1152);
    wconv_kernel<<<dim3(6, 6), 256, 0, stream>>>(pw + (size_t)i * 147456, wq + 442368, 384, 384);
    wconv_kernel<<<dim3(24, 6), 256, 0, stream>>>(w1 + (size_t)i * 589824, wq + 589824, 384, 1536);
    wconv_kernel<<<dim3(6, 24), 256, 0, stream>>>(w2 + (size_t)i * 589824, wq + 1179648, 1536, 384);
  }

  for (int i = 0; i < NBLK; ++i) {
    const float* xin = (i == 0) ? x : out;
    int shift = (i & 1) ? 4 : 0;
    unsigned short* wq = wt + (size_t)i * 1769472;
    ln_fused_kernel<<<8192, 256, 0, stream>>>(xin, og + i * 384, ob + i * 384,
                                              n1g + i * 384, n1b + i * 384, y0h, a_bf, shift);
    gemm_kernel<0, 1152, 384><<<dim3(9, 256), 256, 0, stream>>>(
        a_bf, wq, qkvb + i * 1152, nullptr, big_bf, nullptr, nullptr, 0);
    bias_prep_kernel<<<192, 256, 0, stream>>>(rpb + i * 2700, biasT);
    attn_mfma_kernel<<<1536, 256, 0, stream>>>(big_bf, biasT, at_bf, shift ? 1 : 0);
    gemm_kernel<2, 384, 384><<<dim3(3, 256), 256, 0, stream>>>(
        at_bf, wq + 442368, pb + i * 384, nullptr, x1h, y0h, nullptr, shift);
    ln2_kernel<<<8192, 256, 0, stream>>>(x1h, n2g + i * 384, n2b + i * 384, a_bf);
    gemm_kernel<1, 1536, 384><<<dim3(12, 256), 256, 0, stream>>>(
        a_bf, wq + 589824, b1 + i * 1536, nullptr, big_bf, nullptr, nullptr, 0);
    gemm_kernel<3, 384, 1536><<<dim3(3, 256), 256, 0, stream>>>(
        big_bf, wq + 1179648, b2 + i * 384, out, nullptr, x1h, xin, 0);
  }
}

// Round 9
// 709.309 us; speedup vs baseline: 1.0117x; 1.0117x over previous
//
#include <hip/hip_runtime.h>
#include <hip/hip_bf16.h>

#define BATCH 8
#define HDIM 64
#define WDIM 64
#define CC 384
#define NHE 12
#define HD 32
#define NTOK 32768  // BATCH*HDIM*WDIM
#define NBLK 2

typedef short short8 __attribute__((ext_vector_type(8)));
typedef float f32x4 __attribute__((ext_vector_type(4)));

__device__ __forceinline__ float bf2f(unsigned short u) {
  return __uint_as_float(((unsigned int)u) << 16);
}
__device__ __forceinline__ unsigned short f2bf(float f) {
  __hip_bfloat16 h = __float2bfloat16(f);
  return *reinterpret_cast<unsigned short*>(&h);
}
__device__ __forceinline__ float wave_sum(float s) {
#pragma unroll
  for (int o = 32; o; o >>= 1) s += __shfl_xor(s, o, 64);
  return s;
}
__device__ __forceinline__ float gelu_f(float x) {
  float y = 0.7978845608028654f * (x + 0.044715f * x * x * x);
  float t = 1.0f - 2.0f / (__expf(2.0f * y) + 1.0f);
  return 0.5f * x * (1.0f + t);
}
__device__ __forceinline__ int regid(int x) {
  return x < 56 ? 0 : (x < 60 ? 1 : 2);
}
// async global->LDS, 16B per lane; lds dest = wave-uniform base + lane*16
__device__ __forceinline__ void gload16(const void* g, void* l) {
  __builtin_amdgcn_global_load_lds(
      (const __attribute__((address_space(1))) unsigned int*)g,
      (__attribute__((address_space(3))) unsigned int*)l, 16, 0, 0);
}

// ---- weight transpose + bf16 cast: src (K,N) f32 -> dst (N,K) bf16 ----
__global__ __launch_bounds__(256) void wconv_kernel(
    const float* __restrict__ src, unsigned short* __restrict__ dst, int K, int N) {
  __shared__ float tile[64 * 65];
  const int bn = blockIdx.x * 64, bk = blockIdx.y * 64;
  const int t = threadIdx.x;
  const int lk = t >> 2, ln = (t & 3) * 16;
  const float* ps = src + (size_t)(bk + lk) * N + bn + ln;
#pragma unroll
  for (int j = 0; j < 4; ++j)
    *(float4*)&tile[lk * 65 + ln + 4 * j] = *(const float4*)(ps + 4 * j);
  __syncthreads();
  const int on = t >> 2, ok = (t & 3) * 16;
  unsigned short ob[16];
#pragma unroll
  for (int j = 0; j < 16; ++j) ob[j] = f2bf(tile[(ok + j) * 65 + on]);
  uint4* pd = (uint4*)(dst + (size_t)(bn + on) * K + bk + ok);
  pd[0] = ((const uint4*)ob)[0];
  pd[1] = ((const uint4*)ob)[1];
}

// ---- bias table prep: biasT[h][n][m] = rpb[relidx(n,m)*12 + h] ----
__global__ __launch_bounds__(256) void bias_prep_kernel(
    const float* __restrict__ rpb, float* __restrict__ biasT) {
  int idx = blockIdx.x * 256 + threadIdx.x;  // 12*64*64 = 49152
  int m = idx & 63;
  int n = (idx >> 6) & 63;
  int h = idx >> 12;
  int dr = (n >> 3) - (m >> 3) + 7;
  int dc = (n & 7) - (m & 7) + 7;
  biasT[idx] = rpb[(dr * 15 + dc) * NHE + h];
}

// ---- fused outer-LN + LN1 + shift + window partition ----
__global__ __launch_bounds__(256) void ln_fused_kernel(
    const float* __restrict__ xin, const float* __restrict__ og,
    const float* __restrict__ ob, const float* __restrict__ n1g,
    const float* __restrict__ n1b, unsigned short* __restrict__ y0h,
    unsigned short* __restrict__ abuf, int shift) {
  const int lane = threadIdx.x & 63;
  const int token = blockIdx.x * 4 + (threadIdx.x >> 6);
  const float* px = xin + (size_t)token * CC;
  float v[6];
#pragma unroll
  for (int j = 0; j < 6; ++j) v[j] = px[j * 64 + lane];
  float s = 0.f;
#pragma unroll
  for (int j = 0; j < 6; ++j) s += v[j];
  s = wave_sum(s);
  float mean = s * (1.0f / CC);
  float q = 0.f;
#pragma unroll
  for (int j = 0; j < 6; ++j) { float d = v[j] - mean; q += d * d; }
  q = wave_sum(q);
  float rstd = rsqrtf(q * (1.0f / CC) + 1e-5f);
  unsigned short* py = y0h + (size_t)token * CC;
#pragma unroll
  for (int j = 0; j < 6; ++j) {
    int d = j * 64 + lane;
    float y = (v[j] - mean) * rstd * og[d] + ob[d];
    py[d] = f2bf(y);
    v[j] = y;
  }
  s = 0.f;
#pragma unroll
  for (int j = 0; j < 6; ++j) s += v[j];
  s = wave_sum(s);
  float mean2 = s * (1.0f / CC);
  q = 0.f;
#pragma unroll
  for (int j = 0; j < 6; ++j) { float d = v[j] - mean2; q += d * d; }
  q = wave_sum(q);
  float rstd2 = rsqrtf(q * (1.0f / CC) + 1e-5f);
  int b = token >> 12;
  int hh = (token >> 6) & 63;
  int ww = token & 63;
  int r = (hh - shift) & 63;
  int c = (ww - shift) & 63;
  int wrow = (((b << 6) + ((r >> 3) << 3) + (c >> 3)) << 6) + ((r & 7) << 3) + (c & 7);
  unsigned short* pa = abuf + (size_t)wrow * CC;
#pragma unroll
  for (int j = 0; j < 6; ++j) {
    int d = j * 64 + lane;
    pa[d] = f2bf((v[j] - mean2) * rstd2 * n1g[d] + n1b[d]);
  }
}

// ---- fused attention + proj + LN2 (one block per window, 4 waves) ----
// Pass p (0..2): wave wv computes head h=4p+wv (MFMA attn, R2-verified math),
// O slice (64 x 128 for 4 heads) assembled in LDS; proj GEMM partial-accumulates
// A from LDS, B (pw^T) from L2 register loads. Epilogue: +pb, un-shift scatter,
// +y0 residual, block-wide LN2 (shfl + LDS row stats) -> x1h and abuf.
// LDS: 4 x 12288 wave scratch (P 8K XOR | Vt 4K XOR; Ol f32 stride-34 overlays)
// + Obuf 16384 (XOR chunks) = 65536. part/stats overlay Obuf in epilogue.
__global__ __launch_bounds__(256, 1) void apl_kernel(
    const unsigned short* __restrict__ qkv, const float* __restrict__ biasT,
    const unsigned short* __restrict__ y0h, const unsigned short* __restrict__ Btp,
    const float* __restrict__ pb, const float* __restrict__ g2,
    const float* __restrict__ b2, unsigned short* __restrict__ x1h,
    unsigned short* __restrict__ abuf, int shift) {
  __shared__ __align__(1024) char smem[65536];
  const int tid = threadIdx.x;
  const int wv = tid >> 6;
  const int lane = tid & 63;
  const int l0 = lane & 15;
  const int q = lane >> 4;
  const int wi = blockIdx.x;
  const int use_mask = (shift != 0);

  unsigned short* P16 = (unsigned short*)(smem + wv * 12288);
  unsigned short* Vt16 = (unsigned short*)(smem + wv * 12288 + 8192);
  float* Ol = (float*)(smem + wv * 12288);   // overlays P+Vt after O-MFMA
  unsigned short* Obuf = (unsigned short*)(smem + 49152);  // 64 x 128 shorts

  f32x4 pacc[4][6] = {};

  for (int p = 0; p < 3; ++p) {
    const int h = 4 * p + wv;
    const unsigned short* qbase = qkv + (size_t)(wi * 64) * 1152 + h * HD;
    short8 kf[4], qf[4];
#pragma unroll
    for (int mt = 0; mt < 4; ++mt)
      kf[mt] = *(const short8*)(qbase + (size_t)(16 * mt + l0) * 1152 + CC + 8 * q);
#pragma unroll
    for (int nt = 0; nt < 4; ++nt)
      qf[nt] = *(const short8*)(qbase + (size_t)(16 * nt + l0) * 1152 + 8 * q);

    f32x4 acc[4][4];
    const float* bh = biasT + h * 4096;
#pragma unroll
    for (int mt = 0; mt < 4; ++mt)
#pragma unroll
      for (int nt = 0; nt < 4; ++nt)
        acc[mt][nt] = *(const f32x4*)(bh + (l0 + 16 * nt) * 64 + 16 * mt + 4 * q);

    // stage V^T (rows d, cols token) with XOR-swizzled 8-short chunks
    {
      unsigned short varr[32];
      const uint4* pv = (const uint4*)(qbase + (size_t)lane * 1152 + 2 * CC);
      uint4* t4 = (uint4*)varr;
      t4[0] = pv[0]; t4[1] = pv[1]; t4[2] = pv[2]; t4[3] = pv[3];
#pragma unroll
      for (int d = 0; d < 32; ++d)
        Vt16[d * 64 + 8 * ((lane >> 3) ^ (d & 7)) + (lane & 7)] = varr[d];
    }

#pragma unroll
    for (int mt = 0; mt < 4; ++mt)
#pragma unroll
      for (int nt = 0; nt < 4; ++nt)
        acc[mt][nt] = __builtin_amdgcn_mfma_f32_16x16x32_bf16(kf[mt], qf[nt], acc[mt][nt], 0, 0, 0);

    if (use_mask) {
      int wloc = wi & 63;
      int wy = (wloc >> 3) * 8, wx = (wloc & 7) * 8;
      int idn[4], idm[16];
#pragma unroll
      for (int nt = 0; nt < 4; ++nt) {
        int n = l0 + 16 * nt;
        idn[nt] = regid(wy + (n >> 3)) * 3 + regid(wx + (n & 7));
      }
#pragma unroll
      for (int mt = 0; mt < 4; ++mt)
#pragma unroll
        for (int r = 0; r < 4; ++r) {
          int m = 16 * mt + 4 * q + r;
          idm[mt * 4 + r] = regid(wy + (m >> 3)) * 3 + regid(wx + (m & 7));
        }
#pragma unroll
      for (int mt = 0; mt < 4; ++mt)
#pragma unroll
        for (int nt = 0; nt < 4; ++nt)
#pragma unroll
          for (int r = 0; r < 4; ++r)
            acc[mt][nt][r] += (idm[mt * 4 + r] == idn[nt]) ? 0.0f : -100.0f;
    }

    float inv[4];
#pragma unroll
    for (int nt = 0; nt < 4; ++nt) {
      float m0 = -1e30f;
#pragma unroll
      for (int mt = 0; mt < 4; ++mt)
#pragma unroll
        for (int r = 0; r < 4; ++r) m0 = fmaxf(m0, acc[mt][nt][r]);
      m0 = fmaxf(m0, __shfl_xor(m0, 16, 64));
      m0 = fmaxf(m0, __shfl_xor(m0, 32, 64));
      float s0 = 0.f;
#pragma unroll
      for (int mt = 0; mt < 4; ++mt)
#pragma unroll
        for (int r = 0; r < 4; ++r) {
          float e = __expf(acc[mt][nt][r] - m0);
          acc[mt][nt][r] = e;
          s0 += e;
        }
      s0 += __shfl_xor(s0, 16, 64);
      s0 += __shfl_xor(s0, 32, 64);
      inv[nt] = 1.0f / s0;
    }

    // write normalized P: row n, element m at chunk (2mt+(q>>1))^(n&7), off 4(q&1)
#pragma unroll
    for (int mt = 0; mt < 4; ++mt)
#pragma unroll
      for (int nt = 0; nt < 4; ++nt) {
        unsigned int lo = (unsigned int)f2bf(acc[mt][nt][0] * inv[nt]) |
                          ((unsigned int)f2bf(acc[mt][nt][1] * inv[nt]) << 16);
        unsigned int hi = (unsigned int)f2bf(acc[mt][nt][2] * inv[nt]) |
                          ((unsigned int)f2bf(acc[mt][nt][3] * inv[nt]) << 16);
        unsigned int* dst = (unsigned int*)&P16[(l0 + 16 * nt) * 64 +
                                                8 * ((2 * mt + (q >> 1)) ^ (l0 & 7)) + 4 * (q & 1)];
        dst[0] = lo;
        dst[1] = hi;
      }
    __syncthreads();

    f32x4 oacc[4][2] = {};
#pragma unroll
    for (int kt = 0; kt < 2; ++kt) {
      short8 pa[4], vb[2];
#pragma unroll
      for (int nt = 0; nt < 4; ++nt)
        pa[nt] = *(const short8*)&P16[(l0 + 16 * nt) * 64 + 8 * ((q + 4 * kt) ^ (l0 & 7))];
#pragma unroll
      for (int dt = 0; dt < 2; ++dt)
        vb[dt] = *(const short8*)&Vt16[(l0 + 16 * dt) * 64 + 8 * ((q + 4 * kt) ^ (l0 & 7))];
#pragma unroll
      for (int nt = 0; nt < 4; ++nt)
#pragma unroll
        for (int dt = 0; dt < 2; ++dt)
          oacc[nt][dt] = __builtin_amdgcn_mfma_f32_16x16x32_bf16(pa[nt], vb[dt], oacc[nt][dt], 0, 0, 0);
    }
    __syncthreads();

    // transpose O through Ol (f32, stride 34 -> 2 lanes/bank)
#pragma unroll
    for (int nt = 0; nt < 4; ++nt)
#pragma unroll
      for (int dt = 0; dt < 2; ++dt)
#pragma unroll
        for (int r = 0; r < 4; ++r)
          Ol[(16 * nt + 4 * q + r) * 34 + l0 + 16 * dt] = oacc[nt][dt][r];
    __syncthreads();

    // Obuf: row token=lane, local k = 32wv + jj*8 + e, chunk XOR-swizzled
#pragma unroll
    for (int jj = 0; jj < 4; ++jj) {
      int c = 4 * wv + jj;
      int pos = (c & 8) | ((c ^ lane) & 7);
      unsigned short tmp[8];
#pragma unroll
      for (int e = 0; e < 8; ++e) tmp[e] = f2bf(Ol[lane * 34 + jj * 8 + e]);
      *(uint4*)&Obuf[lane * 128 + pos * 8] = *(const uint4*)tmp;
    }
    __syncthreads();

    // proj partial accumulate over this 128-k slice
#pragma unroll
    for (int kfl = 0; kfl < 4; ++kfl) {
      short8 a[4], b[6];
      int c2 = kfl * 4 + q;
      int pos2 = (c2 & 8) | ((c2 ^ l0) & 7);
#pragma unroll
      for (int mt = 0; mt < 4; ++mt)
        a[mt] = *(const short8*)&Obuf[(16 * mt + l0) * 128 + pos2 * 8];
#pragma unroll
      for (int nt = 0; nt < 6; ++nt)
        b[nt] = *(const short8*)(Btp + (size_t)(wv * 96 + nt * 16 + l0) * 384 +
                                 128 * p + 32 * kfl + 8 * q);
#pragma unroll
      for (int mt = 0; mt < 4; ++mt)
#pragma unroll
        for (int nt = 0; nt < 6; ++nt)
          pacc[mt][nt] = __builtin_amdgcn_mfma_f32_16x16x32_bf16(a[mt], b[nt], pacc[mt][nt], 0, 0, 0);
    }
    __syncthreads();
  }

  // ---- epilogue: +pb, un-shift scatter, +y0 residual, LN2, stores ----
  float pbv[6], g2v[6], b2v[6];
#pragma unroll
  for (int nt = 0; nt < 6; ++nt) {
    int col = wv * 96 + nt * 16 + l0;
    pbv[nt] = pb[col];
    g2v[nt] = g2[col];
    b2v[nt] = b2[col];
  }
  int dstrow[4][4];
#pragma unroll
  for (int mt = 0; mt < 4; ++mt)
#pragma unroll
    for (int rr = 0; rr < 4; ++rr) {
      int m = 16 * mt + 4 * q + rr;
      int grow = wi * 64 + m;
      int b_ = grow >> 12;
      int wl = (grow >> 6) & 63;
      int t = grow & 63;
      int rs = ((wl >> 3) << 3) + (t >> 3);
      int cs = ((wl & 7) << 3) + (t & 7);
      int hh = (rs + shift) & 63;
      int ww = (cs + shift) & 63;
      dstrow[mt][rr] = (((b_ << 6) + hh) << 6) + ww;
    }
#pragma unroll
  for (int mt = 0; mt < 4; ++mt)
#pragma unroll
    for (int nt = 0; nt < 6; ++nt)
#pragma unroll
      for (int rr = 0; rr < 4; ++rr) {
        size_t dst = (size_t)dstrow[mt][rr] * CC + wv * 96 + nt * 16 + l0;
        pacc[mt][nt][rr] += pbv[nt] + bf2f(y0h[dst]);
      }
  float* part = (float*)(smem + 49152);          // overlays Obuf (dead)
  float* stats = (float*)(smem + 49152 + 2048);
#pragma unroll
  for (int mt = 0; mt < 4; ++mt)
#pragma unroll
    for (int rr = 0; rr < 4; ++rr) {
      float s = 0.f, ss = 0.f;
#pragma unroll
      for (int nt = 0; nt < 6; ++nt) {
        float v = pacc[mt][nt][rr];
        s += v;
        ss += v * v;
      }
#pragma unroll
      for (int o = 8; o; o >>= 1) {
        s += __shfl_xor(s, o, 64);
        ss += __shfl_xor(ss, o, 64);
      }
      if (l0 == 0) {
        int m = 16 * mt + 4 * q + rr;
        part[(m * 4 + wv) * 2] = s;
        part[(m * 4 + wv) * 2 + 1] = ss;
      }
    }
  __syncthreads();
  if (tid < 64) {
    float s = 0.f, ss = 0.f;
#pragma unroll
    for (int w = 0; w < 4; ++w) {
      s += part[(tid * 4 + w) * 2];
      ss += part[(tid * 4 + w) * 2 + 1];
    }
    float mean = s * (1.0f / CC);
    float var = ss * (1.0f / CC) - mean * mean;
    stats[tid * 2] = mean;
    stats[tid * 2 + 1] = rsqrtf(var + 1e-5f);
  }
  __syncthreads();
#pragma unroll
  for (int mt = 0; mt < 4; ++mt)
#pragma unroll
    for (int rr = 0; rr < 4; ++rr) {
      int m = 16 * mt + 4 * q + rr;
      float mean = stats[m * 2];
      float rstd = stats[m * 2 + 1];
#pragma unroll
      for (int nt = 0; nt < 6; ++nt) {
        float v = pacc[mt][nt][rr];
        size_t dst = (size_t)dstrow[mt][rr] * CC + wv * 96 + nt * 16 + l0;
        x1h[dst] = f2bf(v);
        abuf[dst] = f2bf((v - mean) * rstd * g2v[nt] + b2v[nt]);
      }
    }
}

// ---- GEMM (R4-proven config): dual A+B DMA->LDS staging, single-buffered,
// BK=64, XOR-swizzled unpadded LDS (0 conflicts), grid x=colTiles (A L2
// temporal affinity), 2 blocks/CU (occupancy-4 explodes WRITE_SIZE: R3/R6).
// EPI 0: +bias, scale q-cols -> bf16 (QKV)
// EPI 1: +bias, gelu -> bf16 (MLP1)
// EPI 3: +bias, + add0h(x1 bf16) + add1f(xv fp32) -> fp32 (MLP2 -> out)
template <int EPI, int NN, int KK>
__global__ __launch_bounds__(256, 2) void gemm_kernel(
    const unsigned short* __restrict__ A, const unsigned short* __restrict__ Bt,
    const float* __restrict__ bias, float* __restrict__ outf,
    unsigned short* __restrict__ outb, const unsigned short* __restrict__ add0h,
    const float* __restrict__ add1f) {
  __shared__ __align__(1024) char smem[32768];  // As 16K | Bs 16K
  unsigned short* As = (unsigned short*)smem;
  unsigned short* Bs = (unsigned short*)(smem + 16384);
  const int tid = threadIdx.x;
  const int lane = tid & 63;
  const int wv = tid >> 6;
  const int wm = wv & 1, wn = wv >> 1;
  const int rowBase = blockIdx.y * 128;
  const int colBase = blockIdx.x * 128;
  const int srow = lane >> 3;
  const int schunk = (lane & 7) ^ srow;  // source chunk so LDS pos p = s ^ (r&7)
  const unsigned short* pA = A + (size_t)(rowBase + srow) * KK + 8 * schunk;
  const unsigned short* pB = Bt + (size_t)(colBase + srow) * KK + 8 * schunk;
  const int l0 = lane & 15;
  const int q = lane >> 4;
  f32x4 acc[4][4] = {};

  for (int k0 = 0; k0 < KK; k0 += 64) {
    __syncthreads();
#pragma unroll
    for (int i = 0; i < 4; ++i) {
      int c = i * 4 + wv;  // 16 chunks of 8 rows each
      gload16(pA + (size_t)(8 * c) * KK + k0, (char*)As + c * 1024);
      gload16(pB + (size_t)(8 * c) * KK + k0, (char*)Bs + c * 1024);
    }
    __syncthreads();
#pragma unroll
    for (int ksub = 0; ksub < 2; ++ksub) {
      const int sc = ksub * 4 + q;
      short8 af[4], bfr[4];
#pragma unroll
      for (int im = 0; im < 4; ++im) {
        int r = wm * 64 + im * 16 + l0;
        af[im] = *(const short8*)&As[r * 64 + 8 * (sc ^ (r & 7))];
      }
#pragma unroll
      for (int in_ = 0; in_ < 4; ++in_) {
        int r = wn * 64 + in_ * 16 + l0;
        bfr[in_] = *(const short8*)&Bs[r * 64 + 8 * (sc ^ (r & 7))];
      }
#pragma unroll
      for (int im = 0; im < 4; ++im)
#pragma unroll
        for (int in_ = 0; in_ < 4; ++in_)
          acc[im][in_] = __builtin_amdgcn_mfma_f32_16x16x32_bf16(
              af[im], bfr[in_], acc[im][in_], 0, 0, 0);
    }
  }
  const int quad = lane >> 4;
  const int lc = lane & 15;
#pragma unroll
  for (int im = 0; im < 4; ++im) {
    int rb = rowBase + wm * 64 + im * 16 + quad * 4;
#pragma unroll
    for (int in_ = 0; in_ < 4; ++in_) {
      int gcol = colBase + wn * 64 + in_ * 16 + lc;
      float bv = bias[gcol];
#pragma unroll
      for (int r = 0; r < 4; ++r) {
        int grow = rb + r;
        float v = acc[im][in_][r] + bv;
        if (EPI == 0) {
          if (gcol < CC) v *= 0.17677669529663687f;  // fold q-scale into QKV
          outb[(size_t)grow * NN + gcol] = f2bf(v);
        } else if (EPI == 1) {
          outb[(size_t)grow * NN + gcol] = f2bf(gelu_f(v));
        } else {
          size_t dst = (size_t)grow * CC + gcol;
          outf[dst] = bf2f(add0h[dst]) + add1f[dst] + v;
        }
      }
    }
  }
}

extern "C" void kernel_launch(void* const* d_in, const int* in_sizes, int n_in,
                              void* d_out, int out_size, void* d_ws, size_t ws_size,
                              hipStream_t stream) {
  const float* x    = (const float*)d_in[0];
  const float* og   = (const float*)d_in[1];
  const float* ob   = (const float*)d_in[2];
  const float* n1g  = (const float*)d_in[3];
  const float* n1b  = (const float*)d_in[4];
  const float* n2g  = (const float*)d_in[5];
  const float* n2b  = (const float*)d_in[6];
  const float* qkvw = (const float*)d_in[7];
  const float* qkvb = (const float*)d_in[8];
  const float* pw   = (const float*)d_in[9];
  const float* pb   = (const float*)d_in[10];
  const float* w1   = (const float*)d_in[11];
  const float* b1   = (const float*)d_in[12];
  const float* w2   = (const float*)d_in[13];
  const float* b2   = (const float*)d_in[14];
  const float* rpb  = (const float*)d_in[15];
  float* out = (float*)d_out;

  char* ws = (char*)d_ws;
  unsigned short* y0h   = (unsigned short*)(ws);              // 25165824 B
  unsigned short* x1h   = (unsigned short*)(ws + 25165824);   // 25165824 B
  unsigned short* a_bf  = (unsigned short*)(ws + 50331648);   // 25165824 B
  unsigned short* big_bf= (unsigned short*)(ws + 100663296);  // 100663296 B (qkv/mlp1 union)
  unsigned short* wt    = (unsigned short*)(ws + 201326592);  // 7077888 B
  float* biasT          = (float*)(ws + 100663296 + 75497472);  // 196608 B (tail of big_bf)

  for (int i = 0; i < NBLK; ++i) {
    unsigned short* wq = wt + (size_t)i * 1769472;
    wconv_kernel<<<dim3(18, 6), 256, 0, stream>>>(qkvw + (size_t)i * 442368, wq, 384, 1152);
    wconv_kernel<<<dim3(6, 6), 256, 0, stream>>>(pw + (size_t)i * 147456, wq + 442368, 384, 384);
    wconv_kernel<<<dim3(24, 6), 256, 0, stream>>>(w1 + (size_t)i * 589824, wq + 589824, 384, 1536);
    wconv_kernel<<<dim3(6, 24), 256, 0, stream>>>(w2 + (size_t)i * 589824, wq + 1179648, 1536, 384);
  }

  for (int i = 0; i < NBLK; ++i) {
    const float* xin = (i == 0) ? x : out;
    int shift = (i & 1) ? 4 : 0;
    unsigned short* wq = wt + (size_t)i * 1769472;
    ln_fused_kernel<<<8192, 256, 0, stream>>>(xin, og + i * 384, ob + i * 384,
                                              n1g + i * 384, n1b + i * 384, y0h, a_bf, shift);
    gemm_kernel<0, 1152, 384><<<dim3(9, 256), 256, 0, stream>>>(
        a_bf, wq, qkvb + i * 1152, nullptr, big_bf, nullptr, nullptr);
    bias_prep_kernel<<<192, 256, 0, stream>>>(rpb + i * 2700, biasT);
    apl_kernel<<<512, 256, 0, stream>>>(big_bf, biasT, y0h, wq + 442368,
                                        pb + i * 384, n2g + i * 384, n2b + i * 384,
                                        x1h, a_bf, shift);
    gemm_kernel<1, 1536, 384><<<dim3(12, 256), 256, 0, stream>>>(
        a_bf, wq + 589824, b1 + i * 1536, nullptr, big_bf, nullptr, nullptr);
    gemm_kernel<3, 384, 1536><<<dim3(3, 256), 256, 0, stream>>>(
        big_bf, wq + 1179648, b2 + i * 384, out, nullptr, x1h, xin);
  }
}